// Round 8
// baseline (240.557 us; speedup 1.0000x reference)
//
#include <hip/hip_runtime.h>
#include <hip/hip_bf16.h>

typedef unsigned short u16;
typedef unsigned int u32;
typedef __attribute__((ext_vector_type(4))) float f32x4;
typedef __attribute__((ext_vector_type(16))) float f32x16;
typedef __attribute__((ext_vector_type(4))) u32 u32x4;
typedef __attribute__((ext_vector_type(8))) __bf16 bf16x8;

#define LAM 20.60992915555662f   // log2(e)/0.07

__device__ __forceinline__ void gl16(const void* g, void* l) {
  __builtin_amdgcn_global_load_lds(
      (const __attribute__((address_space(1))) unsigned int*)g,
      (__attribute__((address_space(3))) unsigned int*)l, 16, 0, 0);
}

__device__ __forceinline__ u32 cvtpk(float a, float b) {
  u32 r;
  asm("v_cvt_pk_bf16_f32 %0, %1, %2" : "=v"(r) : "v"(a), "v"(b));
  return r;
}

__device__ __forceinline__ float exp2a(float x) {
  float r;
  asm("v_exp_f32 %0, %1" : "=v"(r) : "v"(x));
  return r;
}

__device__ __forceinline__ u32 umaxu(u32 a, u32 b) { return a > b ? a : b; }
__device__ __forceinline__ u32 uminu(u32 a, u32 b) { return a < b ? a : b; }

__device__ __forceinline__ float ALf(const float* p) {
  return __hip_atomic_load(p, __ATOMIC_RELAXED, __HIP_MEMORY_SCOPE_AGENT);
}
__device__ __forceinline__ u32 ALu(const u32* p) {
  return __hip_atomic_load(p, __ATOMIC_RELAXED, __HIP_MEMORY_SCOPE_AGENT);
}

// ---------------- Kernel 1: embeddings -> swizzled ehi/elo/et + einv ----------------
__global__ __launch_bounds__(256) void k_eprep(
    const float* __restrict__ emb, float* __restrict__ einv,
    u16* __restrict__ ehi, u16* __restrict__ elo, u16* __restrict__ et,
    float* __restrict__ out) {
  __shared__ u16 ehl[64][72];
  const int ch = blockIdx.x, t = threadIdx.x;
  const int e = t >> 2, q = t & 3;
  const int ge = ch * 64 + e;
  float v[16];
#pragma unroll
  for (int b = 0; b < 4; b++)
    *reinterpret_cast<float4*>(v + 4 * b) =
        *reinterpret_cast<const float4*>(emb + (size_t)ge * 64 + q * 16 + 4 * b);
  float ss = 0.f;
#pragma unroll
  for (int j = 0; j < 16; j++) ss += v[j] * v[j];
  ss += __shfl_xor(ss, 1);
  ss += __shfl_xor(ss, 2);
  float inv = 1.0f / fmaxf(sqrtf(ss), 1e-12f);
  if (q == 0) einv[ge] = inv;
  u16 hi[16], lo[16];
#pragma unroll
  for (int j = 0; j < 16; j++) {
    float n = v[j] * inv;
    __bf16 h = (__bf16)n;
    hi[j] = __builtin_bit_cast(u16, h);
    __bf16 l = (__bf16)(n - (float)h);
    lo[j] = __builtin_bit_cast(u16, l);
  }
  // global swizzled hi/lo writes (16B blocks permuted within the 128B row)
#pragma unroll
  for (int bb = 0; bb < 2; bb++) {
    int b = 2 * q + bb;
    int pos = (b ^ (e & 7)) * 8;
    *reinterpret_cast<uint4*>(ehi + (size_t)ge * 64 + pos) =
        *reinterpret_cast<const uint4*>(hi + 8 * bb);
    *reinterpret_cast<uint4*>(elo + (size_t)ge * 64 + pos) =
        *reinterpret_cast<const uint4*>(lo + 8 * bb);
  }
  *reinterpret_cast<uint4*>(&ehl[e][q * 16]) = *reinterpret_cast<const uint4*>(hi);
  *reinterpret_cast<uint4*>(&ehl[e][q * 16 + 8]) = *reinterpret_cast<const uint4*>(hi + 8);
  __syncthreads();
  // phase 2: et[d][e] swizzled
  {
    const int d = t >> 2, eq = t & 3;
    u16 vals[16];
#pragma unroll
    for (int j = 0; j < 16; j++) vals[j] = ehl[eq * 16 + j][d];
#pragma unroll
    for (int bb = 0; bb < 2; bb++) {
      int b = 2 * eq + bb;
      int pos = (b ^ (d & 7)) * 8;
      *reinterpret_cast<uint4*>(et + (size_t)ch * 4096 + d * 64 + pos) =
          *reinterpret_cast<const uint4*>(vals + 8 * bb);
    }
  }
  if (ch == 0 && t == 0) out[2097152] = 0.0f;  // entropy_loss
}

// ---------------- Kernel 2: fused softmax-VQ (z-prep prologue + finalize epilogue) ---
__global__ __launch_bounds__(256, 4) void k_main(
    const float* __restrict__ z, const float* __restrict__ emb,
    const float* __restrict__ einv,
    const u16* __restrict__ ehi, const u16* __restrict__ elo,
    const u16* __restrict__ et, float* __restrict__ Osum,
    u32* __restrict__ pk1, u32* __restrict__ pk2, int* __restrict__ cnt,
    float* __restrict__ out) {
  __shared__ __align__(16) union SM {
    struct { u16 A[2][2][4096]; u16 V[4096]; } m;                       // 40960 B
    float ztr[4][2304];                                                  // 36864 B
    struct { float olds[64][128]; float part[2][128]; float inv[128]; } f;  // 34304 B
  } sm;
  __shared__ int lastf;

  const int t = threadIdx.x;
  const int w = t >> 6, lane = t & 63;
  const int H = lane >> 5, c = lane & 31;
  const int bx = blockIdx.x;
  const int s = bx >> 8, tile = bx & 255;   // same-tile seg blocks dispatch-separated
  const int px0g = tile * 128;
  const int px = px0g + w * 32 + c;
  const int b_ = px0g >> 12, hw0 = px0g & 4095;

  // ---- prologue: per-wave z transpose + normalize -> Q hi/lo frags in regs ----
  bf16x8 qh[4], ql[4];
  {
    float* zt = &sm.ztr[w][0];  // [64][36] f32
    const float* zb = z + (size_t)b_ * 262144 + hw0 + w * 32;
#pragma unroll
    for (int i = 0; i < 8; i++) {
      int cc = i * 8 + (lane >> 3), col4 = (lane & 7) * 4;
      float4 v = *reinterpret_cast<const float4*>(zb + (size_t)cc * 4096 + col4);
      *reinterpret_cast<float4*>(zt + cc * 36 + col4) = v;
    }
    // per-wave region: compiler inserts lgkmcnt waits; no barrier needed
    const int cpx = lane & 31;
    float val[4][8];
    float ss = 0.f;
#pragma unroll
    for (int kc = 0; kc < 4; kc++)
#pragma unroll
      for (int j = 0; j < 8; j++) {
        float vv = zt[(kc * 16 + 8 * H + j) * 36 + cpx];
        val[kc][j] = vv;
        ss = fmaf(vv, vv, ss);
      }
    ss += __shfl_xor(ss, 32);  // H-partner holds the other 32 channels
    float inv = 1.0f / fmaxf(sqrtf(ss), 1e-12f);
#pragma unroll
    for (int kc = 0; kc < 4; kc++) {
      bf16x8 xh, xl;
#pragma unroll
      for (int j = 0; j < 8; j++) {
        float n = val[kc][j] * inv;
        __bf16 h = (__bf16)n;
        xh[j] = h;
        xl[j] = (__bf16)(n - (float)h);
      }
      qh[kc] = xh;
      ql[kc] = xl;
    }
  }
  __syncthreads();  // zt regions free before staging overwrites them

  // swizzled 16B-block offsets within a 64-u16 row (key = row&7 = c&7)
  int cb[4];
#pragma unroll
  for (int kc = 0; kc < 4; kc++) cb[kc] = 8 * ((2 * kc + H) ^ (c & 7));
  const int row0 = c * 64, row1 = (32 + c) * 64;

  f32x16 O0 = (f32x16)(0.0f), O1 = (f32x16)(0.0f);
  // packed top-2: ((u32)(s*2^18 + 2^19) << 12) | eidx  — fixed-point, monotone
  u32 p1 = 0u, p2 = 0u;
  const u32 vH4 = (u32)(4 * H);

  // prologue: stage ehi/elo chunk 0 into A[0]
  {
    const size_t gb = (size_t)(s * 16) * 4096;
#pragma unroll
    for (int u = 0; u < 2; u++) {
      int off = t * 8 + u * 2048;
      gl16(ehi + gb + off, &sm.m.A[0][0][off]);
      gl16(elo + gb + off, &sm.m.A[0][1][off]);
    }
  }
  __syncthreads();

  for (int ch = 0; ch < 16; ch++) {
    const int cur = ch & 1;
    // stage et[ch] into V (consumed after barrier #1)
    {
      const size_t gv = (size_t)(s * 16 + ch) * 4096;
#pragma unroll
      for (int u = 0; u < 2; u++) {
        int off = t * 8 + u * 2048;
        gl16(et + gv + off, &sm.m.V[off]);
      }
    }
    // stage ehi/elo[ch+1] into the other dbuf half
    if (ch + 1 < 16) {
      const size_t gb = (size_t)(s * 16 + ch + 1) * 4096;
#pragma unroll
      for (int u = 0; u < 2; u++) {
        int off = t * 8 + u * 2048;
        gl16(ehi + gb + off, &sm.m.A[cur ^ 1][0][off]);
        gl16(elo + gb + off, &sm.m.A[cur ^ 1][1][off]);
      }
    }
    const u16* sh = sm.m.A[cur][0];
    const u16* sl = sm.m.A[cur][1];

    // --- swapped QK^T: S^T[e][px], A = E rows, B = Q ---
    f32x16 sa0, sa1;
    {
      f32x16 acc = (f32x16)(0.0f);
#pragma unroll
      for (int kc = 0; kc < 4; kc++) {
        bf16x8 ah = *reinterpret_cast<const bf16x8*>(&sh[row0 + cb[kc]]);
        bf16x8 al = *reinterpret_cast<const bf16x8*>(&sl[row0 + cb[kc]]);
        acc = __builtin_amdgcn_mfma_f32_32x32x16_bf16(ah, qh[kc], acc, 0, 0, 0);
        acc = __builtin_amdgcn_mfma_f32_32x32x16_bf16(al, qh[kc], acc, 0, 0, 0);
        acc = __builtin_amdgcn_mfma_f32_32x32x16_bf16(ah, ql[kc], acc, 0, 0, 0);
      }
      sa0 = acc;
    }
    {
      f32x16 acc = (f32x16)(0.0f);
#pragma unroll
      for (int kc = 0; kc < 4; kc++) {
        bf16x8 ah = *reinterpret_cast<const bf16x8*>(&sh[row1 + cb[kc]]);
        bf16x8 al = *reinterpret_cast<const bf16x8*>(&sl[row1 + cb[kc]]);
        acc = __builtin_amdgcn_mfma_f32_32x32x16_bf16(ah, qh[kc], acc, 0, 0, 0);
        acc = __builtin_amdgcn_mfma_f32_32x32x16_bf16(al, qh[kc], acc, 0, 0, 0);
        acc = __builtin_amdgcn_mfma_f32_32x32x16_bf16(ah, ql[kc], acc, 0, 0, 0);
      }
      sa1 = acc;
    }

    // --- p = exp2(LAM*S - LAM); packed top-2 (fixed-point 20b score | 12b idx) ---
    const int e0 = (s * 16 + ch) * 64;
    u32 pk[2][8];
#pragma unroll
    for (int nt = 0; nt < 2; nt++) {
      float pe[16];
#pragma unroll
      for (int reg = 0; reg < 16; reg++) {
        float svv = nt ? sa1[reg] : sa0[reg];
        u32 tfix = (u32)fmaf(svv, 262144.0f, 524288.0f);  // 2^18, 2^19
        u32 pckd = (tfix << 12) |
                   ((u32)(e0 + nt * 32 + (reg & 3) + 8 * (reg >> 2)) | vH4);
        p2 = umaxu(p2, uminu(pckd, p1));
        p1 = umaxu(p1, pckd);
        pe[reg] = exp2a(fmaf(svv, LAM, -LAM));
      }
#pragma unroll
      for (int qq = 0; qq < 8; qq++) pk[nt][qq] = cvtpk(pe[2 * qq], pe[2 * qq + 1]);
    }

    __syncthreads();  // #1: V (and next ehi/elo) staging drained; all waves ready

    // --- PV as O^T = V^T * P^T: B-words built via permlane32_swap ---
#pragma unroll
    for (int km = 0; km < 4; km++) {
      const int nt = km >> 1, m1 = km & 1;
      u32 ax = pk[nt][4 * m1 + 0], bx2 = pk[nt][4 * m1 + 2];
      u32 ay = pk[nt][4 * m1 + 1], by2 = pk[nt][4 * m1 + 3];
      asm("v_permlane32_swap_b32 %0, %1" : "+v"(ax), "+v"(bx2));
      asm("v_permlane32_swap_b32 %0, %1" : "+v"(ay), "+v"(by2));
      u32x4 bv; bv.x = ax; bv.y = ay; bv.z = bx2; bv.w = by2;
      bf16x8 pb = __builtin_bit_cast(bf16x8, bv);
      bf16x8 a0 = *reinterpret_cast<const bf16x8*>(&sm.m.V[row0 + cb[km]]);
      bf16x8 a1 = *reinterpret_cast<const bf16x8*>(&sm.m.V[row1 + cb[km]]);
      O0 = __builtin_amdgcn_mfma_f32_32x32x16_bf16(a0, pb, O0, 0, 0, 0);
      O1 = __builtin_amdgcn_mfma_f32_32x32x16_bf16(a1, pb, O1, 0, 0, 0);
    }
    __syncthreads();  // #2: all waves done reading V and A[cur]
  }

  // --- merge packed top-2 between lane halves (same px) ---
  {
    u32 o1 = (u32)__shfl_xor((int)p1, 32);
    u32 o2 = (u32)__shfl_xor((int)p2, 32);
    u32 n1 = umaxu(p1, o1);
    u32 n2 = umaxu(uminu(p1, o1), umaxu(p2, o2));
    if (H == 0) {
      int o = s * 32768 + px;
      pk1[o] = n1;
      pk2[o] = n2;
    }
  }
  // --- coalesced atomic O accumulate into Osum[d][px] ---
#pragma unroll
  for (int reg = 0; reg < 16; reg++) {
    int d0 = (reg & 3) + 8 * (reg >> 2) + 4 * H;
    unsafeAtomicAdd(&Osum[(size_t)d0 * 32768 + px], O0[reg]);
    unsafeAtomicAdd(&Osum[(size_t)(d0 + 32) * 32768 + px], O1[reg]);
  }

  // ---- completion handoff: last of the 4 seg-blocks finalizes this tile ----
  __threadfence();
  __syncthreads();
  if (t == 0) lastf = atomicAdd(&cnt[tile], 1);
  __syncthreads();
  if (lastf != 3) return;
  __threadfence();

  // ---- finalize: l2norm over d, coalesced stores, packed merge + fp64 argmax ----
#pragma unroll 4
  for (int i = 0; i < 32; i++) {
    int idx = i * 256 + t, d = idx >> 7, pxl = idx & 127;
    sm.f.olds[d][pxl] = ALf(&Osum[(size_t)d * 32768 + px0g + pxl]);
  }
  __syncthreads();
  {
    int pxl = t & 127, dh = t >> 7;
    float ss2 = 0.f;
#pragma unroll 8
    for (int dd = 0; dd < 32; dd++) {
      float v = sm.f.olds[dh * 32 + dd][pxl];
      ss2 = fmaf(v, v, ss2);
    }
    sm.f.part[dh][pxl] = ss2;
  }
  __syncthreads();
  if (t < 128) sm.f.inv[t] = 1.0f / fmaxf(sqrtf(sm.f.part[0][t] + sm.f.part[1][t]), 1e-30f);
  __syncthreads();
#pragma unroll 4
  for (int i = 0; i < 32; i++) {
    int d = 2 * i + (t >> 7), pxl = t & 127;
    out[(size_t)b_ * 262144 + (size_t)d * 4096 + hw0 + pxl] = sm.f.olds[d][pxl] * sm.f.inv[pxl];
  }
  // argmax: 2 threads per px (same wave), fp64 recompute of the two candidates
  {
    const int pxl = t >> 1, half = t & 1;
    const int gpx = px0g + pxl;
    u32 m1 = ALu(&pk1[gpx]), m2 = ALu(&pk2[gpx]);
#pragma unroll
    for (int sg = 1; sg < 4; sg++) {
      u32 a1 = ALu(&pk1[sg * 32768 + gpx]), a2 = ALu(&pk2[sg * 32768 + gpx]);
      u32 t2 = umaxu(umaxu(m2, a2), uminu(m1, a1));
      m1 = umaxu(m1, a1);
      m2 = t2;
    }
    const int j1 = (int)(m1 & 0xFFFu), j2 = (int)(m2 & 0xFFFu);
    const float* zc = z + (size_t)b_ * 262144 + hw0 + pxl;
    const float* e1 = emb + (size_t)j1 * 64;
    const float* e2 = emb + (size_t)j2 * 64;
    double d1 = 0.0, d2 = 0.0;
#pragma unroll 8
    for (int j = 0; j < 32; j++) {
      int cc = half * 32 + j;
      double zv = (double)zc[(size_t)cc * 4096];
      d1 += zv * (double)e1[cc];
      d2 += zv * (double)e2[cc];
    }
    d1 += __shfl_xor(d1, 1);
    d2 += __shfl_xor(d2, 1);
    d1 *= (double)einv[j1];
    d2 *= (double)einv[j2];
    if (half == 0) {
      int best = (d2 > d1 || (d2 == d1 && j2 < j1)) ? j2 : j1;
      out[2097153 + gpx] = (float)best;
    }
  }
}

extern "C" void kernel_launch(void* const* d_in, const int* in_sizes, int n_in,
                              void* d_out, int out_size, void* d_ws, size_t ws_size,
                              hipStream_t stream) {
  const float* z = (const float*)d_in[0];
  const float* emb = (const float*)d_in[1];
  float* out = (float*)d_out;
  char* ws = (char*)d_ws;
  // workspace layout (bytes), total 11551744
  float* Osum = (float*)(ws + 0);          // [64][32768] fp32 = 8388608
  int*   cnt  = (int*)(ws + 8388608);      // 256 tile counters (pad to 1024)
  u32*   pk1  = (u32*)(ws + 8389632);      // 4*32768*4 = 524288
  u32*   pk2  = (u32*)(ws + 8913920);      // 524288
  u16*   ehi  = (u16*)(ws + 9438208);      // 524288
  u16*   elo  = (u16*)(ws + 9962496);      // 524288
  u16*   et   = (u16*)(ws + 10486784);     // 524288
  float* einv = (float*)(ws + 11011072);   // 16384

  hipMemsetAsync(ws, 0, 8389632, stream);  // Osum + cnt
  k_eprep<<<dim3(64), dim3(256), 0, stream>>>(emb, einv, ehi, elo, et, out);
  k_main<<<dim3(1024), dim3(256), 0, stream>>>(z, emb, einv, ehi, elo, et,
                                               Osum, pk1, pk2, cnt, out);
}